// Round 14
// baseline (192.400 us; speedup 1.0000x reference)
//
#include <hip/hip_runtime.h>

#define IN_DIM 256
#define OUT_DIM 128
#define LEAKY 0.01f
#define GEMM_BLOCKS 391   // 782 tiles / 391 = exactly 2 tiles per block
#define NSLICE 8          // 16-col slices: 100K*16*2B = 3.2 MB -> fits 4MB L2
#define SP_ROWS 128       // rows per spmm block (2 lanes/row)
#define SP_CAP 3072       // LDS edge capacity (Poisson(2048): +22 sigma)

typedef __attribute__((ext_vector_type(8))) short bf16x8;
typedef __attribute__((ext_vector_type(4))) float f32x4;
typedef __attribute__((ext_vector_type(4))) unsigned u32x4;

// RNE f32->bf16 pack (2 at a time). No builtin on gfx950 -> inline asm.
__device__ inline unsigned cvtpk_bf16(float lo, float hi) {
  unsigned r;
  asm volatile("v_cvt_pk_bf16_f32 %0, %1, %2" : "=v"(r) : "v"(lo), "v"(hi));
  return r;
}

// unpack a u32 holding two bf16 (little-endian: low short = even col)
__device__ inline float blo(unsigned u) {
  union { unsigned x; float f; } c; c.x = u << 16; return c.f;
}
__device__ inline float bhi(unsigned u) {
  union { unsigned x; float f; } c; c.x = u & 0xFFFF0000u; return c.f;
}
__device__ inline float asf(unsigned u) {
  union { unsigned x; float f; } c; c.x = u; return c.f;
}

// LDS swizzle for a [rows][256bf16] tile, measured 0 bank conflicts (R4/R8):
// 16B unit u of row r lives at byte r*512 + ((u&16)<<4) + (((u&15)^(r&15))<<4)
__device__ inline int swz_byte(int r, int u) {
  return r * 512 + ((u & 16) << 4) + (((u & 15) ^ (r & 15)) << 4);
}

// ---------------------------------------------------------------------------
// Kernel 1 (fused): blocks < GEMM_BLOCKS run the MFMA GEMM (W cvt'd
// fp32->bf16 into swizzled LDS, features direct from global, exactly 2 tiles
// per block); blocks >= GEMM_BLOCKS run the adjacent-difference scan.
// Support is written SLICE-MAJOR [8][nrows][16] (validated in R12).
// ---------------------------------------------------------------------------
__global__ __launch_bounds__(512, 4) void gemm_scan(
    const float* __restrict__ feat, const float* __restrict__ w,
    const int* __restrict__ erows, unsigned short* __restrict__ support,
    int* __restrict__ rs, int nrows, int nedges, int ntiles) {
  if (blockIdx.x >= GEMM_BLOCKS) {
    // ---- scan: rs[r] = lower_bound(erows, r), sentinel rs[nrows] ----
    const int i = (blockIdx.x - GEMM_BLOCKS) * 512 + threadIdx.x;
    if (i >= nedges) return;
    const int cur  = erows[i];
    const int prev = (i == 0) ? -1 : erows[i - 1];
    for (int r = prev + 1; r <= cur; ++r) rs[r] = i;
    if (i == nedges - 1)
      for (int r = cur + 1; r <= nrows; ++r) rs[r] = nedges;
    return;
  }

  // ---- GEMM part ----
  __shared__ alignas(16) unsigned short wlds[128 * 256];  // 64 KB, swizzled
  char* wb = reinterpret_cast<char*>(wlds);

  const int t = threadIdx.x;
#pragma unroll
  for (int it = 0; it < 8; ++it) {
    const int g = it * 512 + t;  // unit index 0..4095
    const int r = g >> 5;        // W row 0..127
    const int u = g & 31;        // 16B unit within row
    const float* src = w + r * IN_DIM + u * 8;
    const float4 a = *reinterpret_cast<const float4*>(src);
    const float4 b = *reinterpret_cast<const float4*>(src + 4);
    uint4 pk;
    pk.x = cvtpk_bf16(a.x, a.y);
    pk.y = cvtpk_bf16(a.z, a.w);
    pk.z = cvtpk_bf16(b.x, b.y);
    pk.w = cvtpk_bf16(b.z, b.w);
    *reinterpret_cast<uint4*>(wb + swz_byte(r, u)) = pk;
  }
  __syncthreads();

  const int wid  = t >> 6;
  const int lane = t & 63;
  const int lrow = lane & 15;
  const int hi   = lane >> 4;
  const size_t slice_stride = (size_t)nrows * 16;

  for (int tile = blockIdx.x; tile < ntiles; tile += GEMM_BLOCKS) {
    const int mrow = tile * 128 + wid * 16 + lrow;
    const int mr   = mrow < nrows ? mrow : nrows - 1;
    const float* fp = feat + mr * IN_DIM + hi * 8;

    f32x4 acc[8];
#pragma unroll
    for (int nt = 0; nt < 8; ++nt) acc[nt] = (f32x4){0.f, 0.f, 0.f, 0.f};

#pragma unroll
    for (int ks = 0; ks < 8; ++ks) {
      const float4 a = *reinterpret_cast<const float4*>(fp + ks * 32);
      const float4 b = *reinterpret_cast<const float4*>(fp + ks * 32 + 4);
      union { bf16x8 v; unsigned u[4]; } bf;
      bf.u[0] = cvtpk_bf16(a.x, a.y);
      bf.u[1] = cvtpk_bf16(a.z, a.w);
      bf.u[2] = cvtpk_bf16(b.x, b.y);
      bf.u[3] = cvtpk_bf16(b.z, b.w);
      const int u = ks * 4 + hi;
#pragma unroll
      for (int nt = 0; nt < 8; ++nt) {
        const bf16x8 af = *reinterpret_cast<const bf16x8*>(
            wb + swz_byte(nt * 16 + lrow, u));
        acc[nt] = __builtin_amdgcn_mfma_f32_16x16x32_bf16(af, bf.v, acc[nt],
                                                          0, 0, 0);
      }
    }

    if (mrow < nrows) {
      // slice-major: cols nt*16 + hi*4 + [0,4) -> slice nt, offset hi*4
#pragma unroll
      for (int nt = 0; nt < 8; ++nt) {
        f32x4 v = acc[nt];
        float a0 = v[0] > 0.f ? v[0] : LEAKY * v[0];
        float a1 = v[1] > 0.f ? v[1] : LEAKY * v[1];
        float a2 = v[2] > 0.f ? v[2] : LEAKY * v[2];
        float a3 = v[3] > 0.f ? v[3] : LEAKY * v[3];
        uint2 st;
        st.x = cvtpk_bf16(a0, a1);
        st.y = cvtpk_bf16(a2, a3);
        unsigned short* o =
            support + nt * slice_stride + (size_t)mrow * 16 + hi * 4;
        *reinterpret_cast<uint2*>(o) = st;
      }
    }
  }
}

// ---------------------------------------------------------------------------
// Kernel 2: out[r] = sum over edges (r,c,v) of v * support[c]
// Slice-phased locality WITHOUT R12's overhead:
//  - block = 128 rows x 2 lanes; block's contiguous edge range staged into
//    LDS once (global-read fallback branch for the >SP_CAP case);
//  - slice loop OUTER (8 x 16-col slices; active slice = 3.2 MB, L2-fits;
//    uniform co-resident blocks stay phase-aligned), edges inner in R10's
//    proven batch-8 (8 LDS ev reads -> 8 x 16B gathers -> FMAs);
//  - lane (row, h): h = 16B half of the 32B slice row -> no cross-lane
//    reduce; normal stores so L2 merges per-slice 64B fragments into lines.
// Instruction counts ~= R10; HBM re-fetch of support eliminated.
// ---------------------------------------------------------------------------
__global__ __launch_bounds__(256) void spmm_slice(
    const int* __restrict__ rs, const int* __restrict__ ecols,
    const float* __restrict__ evals, const unsigned short* __restrict__ support,
    float* __restrict__ out, int nrows) {
  __shared__ uint2 lev[SP_CAP];
  const int t    = threadIdx.x;
  const int r0   = blockIdx.x * SP_ROWS;
  const int rend = (r0 + SP_ROWS < nrows) ? r0 + SP_ROWS : nrows;
  const int cs   = rs[r0];
  const int ce   = rs[rend];
  const int cnt  = ce - cs;

  // stage this block's edge range into LDS (coalesced, up to SP_CAP)
  const int lim = cnt < SP_CAP ? cnt : SP_CAP;
  for (int k = t; k < lim; k += 256)
    lev[k] = make_uint2((unsigned)ecols[cs + k], __float_as_uint(evals[cs + k]));
  __syncthreads();

  const int row = r0 + (t >> 1);
  const int h   = t & 1;
  if (row >= nrows) return;

  const int s_ = rs[row] - cs;
  const int e_ = rs[row + 1] - cs;

  for (int s = 0; s < NSLICE; ++s) {
    const unsigned short* sbase = support + (size_t)s * nrows * 16 + h * 8;
    f32x4 aA = {0.f, 0.f, 0.f, 0.f}, aB = {0.f, 0.f, 0.f, 0.f};

    for (int base = s_; base < e_; base += 8) {
      unsigned cj[8];
      float    vj[8];
#pragma unroll
      for (int j = 0; j < 8; ++j) {
        int k = base + j;
        const bool ok = k < e_;
        k = ok ? k : e_ - 1;
        uint2 p;
        if (k < SP_CAP) {
          p = lev[k];
        } else {  // never taken for this dataset; correctness guard
          p = make_uint2((unsigned)ecols[cs + k],
                         __float_as_uint(evals[cs + k]));
        }
        cj[j] = p.x;
        vj[j] = ok ? asf(p.y) : 0.f;
      }
#pragma unroll
      for (int j = 0; j < 8; ++j) {
        const u32x4 u =
            *reinterpret_cast<const u32x4*>(sbase + (size_t)cj[j] * 16);
        const float v = vj[j];
        aA[0] += v * blo(u[0]);
        aA[1] += v * bhi(u[0]);
        aA[2] += v * blo(u[1]);
        aA[3] += v * bhi(u[1]);
        aB[0] += v * blo(u[2]);
        aB[1] += v * bhi(u[2]);
        aB[2] += v * blo(u[3]);
        aB[3] += v * bhi(u[3]);
      }
    }

    float* o = out + (size_t)row * OUT_DIM + s * 16 + h * 8;
    *reinterpret_cast<f32x4*>(o)     = aA;
    *reinterpret_cast<f32x4*>(o + 4) = aB;
  }
}

// ---------------------------------------------------------------------------
extern "C" void kernel_launch(void* const* d_in, const int* in_sizes, int n_in,
                              void* d_out, int out_size, void* d_ws,
                              size_t ws_size, hipStream_t stream) {
  const float* features = (const float*)d_in[0];
  const float* weight   = (const float*)d_in[1];
  const int*   erows    = (const int*)d_in[2];
  const int*   ecols    = (const int*)d_in[3];
  const float* evals    = (const float*)d_in[4];
  float*       out      = (float*)d_out;

  const int nrows  = in_sizes[0] / IN_DIM;  // 100000
  const int nedges = in_sizes[2];           // 1600000

  // ws layout: support bf16 slice-major (25.6 MB) | row_starts (400 KB)
  unsigned short* support = (unsigned short*)d_ws;
  int* rs = (int*)((char*)d_ws + (size_t)nrows * OUT_DIM * 2);

  const int ntiles      = (nrows + 127) / 128;  // 782 = 2 * GEMM_BLOCKS
  const int scan_blocks = (nedges + 511) / 512;

  gemm_scan<<<GEMM_BLOCKS + scan_blocks, 512, 0, stream>>>(
      features, weight, erows, support, rs, nrows, nedges, ntiles);
  spmm_slice<<<(nrows + SP_ROWS - 1) / SP_ROWS, 256, 0, stream>>>(
      rs, ecols, evals, support, out, nrows);
}